// Round 5
// baseline (343.325 us; speedup 1.0000x reference)
//
#include <hip/hip_runtime.h>

typedef unsigned short u16;
typedef unsigned int   u32;
using bf16x8 = __attribute__((ext_vector_type(8))) __bf16;
using f32x4  = __attribute__((ext_vector_type(4))) float;

#define MFMA16(a,b,c) __builtin_amdgcn_mfma_f32_16x16x32_bf16(a,b,c,0,0,0)

__device__ __forceinline__ float b2f(u16 u){ u32 x = ((u32)u) << 16; return __builtin_bit_cast(float, x); }
__device__ __forceinline__ u16 f2b(float f){
    u32 x = __builtin_bit_cast(u32, f);
    return (u16)((x + 0x7fffu + ((x >> 16) & 1u)) >> 16);
}
__device__ __forceinline__ u32 pk2(float a, float b){ return (u32)f2b(a) | ((u32)f2b(b) << 16); }

// ---------------------------------------------------------------------------
// Single fused kernel: LN + QKVG proj + row-wise attention + gate + out-proj.
// FP32 inputs/output (per reference); bf16 MFMA internally, f32 accum.
// Q/K projections use hi/lo-split bf16 (3 MFMA passes) for precision.
// One block per row i (grid 256). Static LDS = 65024 B.
// ---------------------------------------------------------------------------
constexpr int LDZ = 136;   // per-wave transpose tile row stride (272 B)
constexpr int LDW = 136;   // QKVG W-slice row stride
constexpr int LDO = 40;    // Wo-slice row stride (80 B, 16B-aligned)
constexpr int LDK = 40;    // kh[token][c]
constexpr int LDV = 264;   // vt[c][token] (528 B rows)

__global__ __launch_bounds__(256, 1) void k_fused(
    const float* __restrict__ z, const float* __restrict__ lns, const float* __restrict__ lnb,
    const float* __restrict__ Wq, const float* __restrict__ Wk, const float* __restrict__ Wv,
    const float* __restrict__ Wg, const float* __restrict__ bg,
    const float* __restrict__ Wo, const float* __restrict__ bo,
    float* __restrict__ out)
{
    __shared__ __attribute__((aligned(16))) u16 lnt[4 * 16 * LDZ]; // 17408 B per-wave tiles
    __shared__ __attribute__((aligned(16))) u16 wbuf[5120];        // 10240 B (QKVG 32xLDW | Wo 128xLDO)
    __shared__ __attribute__((aligned(16))) u16 kh[256 * LDK];     // 20480 B
    __shared__ __attribute__((aligned(16))) u16 vt[32 * LDV];      // 16896 B  total 65024 B

    const int i = blockIdx.x;
    const int t = threadIdx.x;
    const int lane = t & 63;
    const int l15  = lane & 15;
    const int quad = lane >> 4;
    const int wave = t >> 6;
    u16* __restrict__ myT = lnt + wave * 16 * LDZ;   // this wave's 16x136 tile

    // ---- per-wave LayerNorm (exact f32) -> hi/lo A-fragments in registers ----
    bf16x8 zfh[4][4], zfl[4][4];   // [m-tile][k-chunk], hi and lo parts
    {
        float sc[32], bi[32];
        #pragma unroll
        for (int u = 0; u < 8; ++u) {
            float4 s4 = *(const float4*)(lns + quad * 32 + u * 4);
            float4 b4 = *(const float4*)(lnb + quad * 32 + u * 4);
            sc[u*4+0]=s4.x; sc[u*4+1]=s4.y; sc[u*4+2]=s4.z; sc[u*4+3]=s4.w;
            bi[u*4+0]=b4.x; bi[u*4+1]=b4.y; bi[u*4+2]=b4.z; bi[u*4+3]=b4.w;
        }
        #pragma unroll 1
        for (int ms = 0; ms < 4; ++ms) {
            const size_t tok = (size_t)(i * 256 + wave * 64 + ms * 16 + l15);
            float x[32];
            #pragma unroll
            for (int u = 0; u < 8; ++u) {
                float4 v4 = *(const float4*)(z + (tok << 7) + quad * 32 + u * 4);
                x[u*4+0]=v4.x; x[u*4+1]=v4.y; x[u*4+2]=v4.z; x[u*4+3]=v4.w;
            }
            float s = 0.f;
            #pragma unroll
            for (int k = 0; k < 32; ++k) s += x[k];
            s += __shfl_xor(s, 16, 64); s += __shfl_xor(s, 32, 64);
            const float mu = s * 0.0078125f;
            float vs = 0.f;
            #pragma unroll
            for (int k = 0; k < 32; ++k) { float d = x[k] - mu; vs += d * d; }
            vs += __shfl_xor(vs, 16, 64); vs += __shfl_xor(vs, 32, 64);
            const float rs = rsqrtf(vs * 0.0078125f + 1e-5f);
            float y[32];
            #pragma unroll
            for (int k = 0; k < 32; ++k) y[k] = (x[k] - mu) * rs * sc[k] + bi[k];
            // hi tile -> frags
            #pragma unroll
            for (int u = 0; u < 4; ++u) {
                uint4 o;
                o.x = pk2(y[u*8+0], y[u*8+1]); o.y = pk2(y[u*8+2], y[u*8+3]);
                o.z = pk2(y[u*8+4], y[u*8+5]); o.w = pk2(y[u*8+6], y[u*8+7]);
                *(uint4*)(myT + l15 * LDZ + quad * 32 + u * 8) = o;
            }
            #pragma unroll
            for (int ks = 0; ks < 4; ++ks)
                zfh[ms][ks] = *(const bf16x8*)(myT + l15 * LDZ + ks * 32 + quad * 8);
            // lo tile -> frags
            #pragma unroll
            for (int k = 0; k < 32; ++k) y[k] -= b2f(f2b(y[k]));
            #pragma unroll
            for (int u = 0; u < 4; ++u) {
                uint4 o;
                o.x = pk2(y[u*8+0], y[u*8+1]); o.y = pk2(y[u*8+2], y[u*8+3]);
                o.z = pk2(y[u*8+4], y[u*8+5]); o.w = pk2(y[u*8+6], y[u*8+7]);
                *(uint4*)(myT + l15 * LDZ + quad * 32 + u * 8) = o;
            }
            #pragma unroll
            for (int ks = 0; ks < 4; ++ks)
                zfl[ms][ks] = *(const bf16x8*)(myT + l15 * LDZ + ks * 32 + quad * 8);
        }
    }

    // stage QKVG head-slice [E=128][32] hi or lo into wbuf[o][e] (B-frag layout)
    auto stageWh = [&](const float* __restrict__ W, int h) {
        for (int c = t; c < 4096; c += 256) {
            const int e = c >> 5, o = c & 31;
            wbuf[o * LDW + e] = f2b(W[e * 128 + h * 32 + o]);
        }
    };
    auto stageWl = [&](const float* __restrict__ W, int h) {
        for (int c = t; c < 4096; c += 256) {
            const int e = c >> 5, o = c & 31;
            const float w = W[e * 128 + h * 32 + o];
            wbuf[o * LDW + e] = f2b(w - b2f(f2b(w)));
        }
    };
    // stage Wo rows [h*32,h*32+32) x [128] into wbuf[n][k] = Wo[h*32+k][n]
    auto stageWoS = [&](int h) {
        for (int c = t; c < 4096; c += 256)
            wbuf[(c & 127) * LDO + (c >> 7)] = f2b(Wo[h * 4096 + c]);
    };
    // GEMM accumulate: 64 tokens (reg A-frags) x staged 32-col W slice
    auto gemmAcc = [&](f32x4 (&acc)[4][2], bf16x8 (&af)[4][4]) {
        #pragma unroll
        for (int ms = 0; ms < 4; ++ms)
            #pragma unroll
            for (int nt = 0; nt < 2; ++nt) {
                f32x4 ac = acc[ms][nt];
                #pragma unroll
                for (int ks = 0; ks < 4; ++ks) {
                    bf16x8 b = *(const bf16x8*)(wbuf + (nt * 16 + l15) * LDW + ks * 32 + quad * 8);
                    ac = MFMA16(af[ms][ks], b, ac);
                }
                acc[ms][nt] = ac;
            }
    };
    auto zero42 = [](f32x4 (&a)[4][2]) {
        #pragma unroll
        for (int ms = 0; ms < 4; ++ms)
            #pragma unroll
            for (int nt = 0; nt < 2; ++nt) a[ms][nt] = f32x4{0.f,0.f,0.f,0.f};
    };

    bf16x8 aq[4];            // Q A-frags (bf16 of accurate q)
    f32x4  ga[4][2];         // sigmoid gate, C-layout
    f32x4  oacc[4][8];       // f32 out-proj accumulators
    #pragma unroll
    for (int ms = 0; ms < 4; ++ms)
        #pragma unroll
        for (int nt = 0; nt < 8; ++nt)
            oacc[ms][nt] = f32x4{0.f, 0.f, 0.f, 0.f};

    #pragma unroll 1
    for (int h = 0; h < 4; ++h) {
        // ---- Q (hi/lo split: znh*Wh + znl*Wh + znh*Wl) ----
        __syncthreads(); stageWh(Wq, h); __syncthreads();
        f32x4 qa[4][2]; zero42(qa);
        gemmAcc(qa, zfh); gemmAcc(qa, zfl);
        __syncthreads(); stageWl(Wq, h); __syncthreads();
        gemmAcc(qa, zfh);
        #pragma unroll
        for (int ms = 0; ms < 4; ++ms) {
            #pragma unroll
            for (int nt = 0; nt < 2; ++nt)
                #pragma unroll
                for (int r = 0; r < 4; ++r)
                    myT[(quad * 4 + r) * LDZ + nt * 16 + l15] = f2b(qa[ms][nt][r]);
            aq[ms] = *(const bf16x8*)(myT + l15 * LDZ + quad * 8);  // same-wave round-trip
        }
        // ---- K (hi/lo split) ----
        __syncthreads(); stageWh(Wk, h); __syncthreads();
        f32x4 ka[4][2]; zero42(ka);
        gemmAcc(ka, zfh); gemmAcc(ka, zfl);
        __syncthreads(); stageWl(Wk, h); __syncthreads();
        gemmAcc(ka, zfh);
        #pragma unroll
        for (int ms = 0; ms < 4; ++ms)
            #pragma unroll
            for (int nt = 0; nt < 2; ++nt)
                #pragma unroll
                for (int r = 0; r < 4; ++r)
                    kh[(wave * 64 + ms * 16 + quad * 4 + r) * LDK + nt * 16 + l15] = f2b(ka[ms][nt][r]);
        // ---- V (hi only, transposed store) ----
        __syncthreads(); stageWh(Wv, h); __syncthreads();
        {
            f32x4 va[4][2]; zero42(va); gemmAcc(va, zfh);
            #pragma unroll
            for (int ms = 0; ms < 4; ++ms)
                #pragma unroll
                for (int nt = 0; nt < 2; ++nt)
                    #pragma unroll
                    for (int r = 0; r < 4; ++r)
                        vt[(nt * 16 + l15) * LDV + wave * 64 + ms * 16 + quad * 4 + r] = f2b(va[ms][nt][r]);
        }
        // ---- G (hi only, sigmoid in regs) ----
        __syncthreads(); stageWh(Wg, h); __syncthreads();
        {
            zero42(ga); gemmAcc(ga, zfh);
            #pragma unroll
            for (int nt = 0; nt < 2; ++nt) {
                const float bb = bg[h * 32 + nt * 16 + l15];
                #pragma unroll
                for (int ms = 0; ms < 4; ++ms)
                    #pragma unroll
                    for (int r = 0; r < 4; ++r)
                        ga[ms][nt][r] = 1.f / (1.f + __expf(-(ga[ms][nt][r] + bb)));
            }
        }
        // ---- Wo slice (also fences kh/vt writes -> attention reads) ----
        __syncthreads(); stageWoS(h); __syncthreads();

        // ---- attention + out-proj accumulate: 4 m-tiles of 16 q-rows ----
        #pragma unroll 1
        for (int it = 0; it < 4; ++it) {
            f32x4 s[16];
            #pragma unroll
            for (int nt = 0; nt < 16; ++nt) {
                bf16x8 b = *(const bf16x8*)(kh + (nt * 16 + l15) * LDK + quad * 8);
                f32x4 zacc = {0.f, 0.f, 0.f, 0.f};
                s[nt] = MFMA16(aq[it], b, zacc);
            }
            float inv[4];
            #pragma unroll
            for (int r = 0; r < 4; ++r) {
                float mx = s[0][r];
                #pragma unroll
                for (int nt = 1; nt < 16; ++nt) mx = fmaxf(mx, s[nt][r]);
                #pragma unroll
                for (int m = 1; m < 16; m <<= 1) mx = fmaxf(mx, __shfl_xor(mx, m, 64));
                float sm = 0.f;
                #pragma unroll
                for (int nt = 0; nt < 16; ++nt) {
                    float e = __expf(s[nt][r] - mx);
                    s[nt][r] = e; sm += e;
                }
                #pragma unroll
                for (int m = 1; m < 16; m <<= 1) sm += __shfl_xor(sm, m, 64);
                inv[r] = 1.f / sm;
            }
            // PV in two 128-col chunks through the per-wave tile
            f32x4 o0 = {0.f,0.f,0.f,0.f}, o1 = {0.f,0.f,0.f,0.f};
            #pragma unroll
            for (int c2 = 0; c2 < 2; ++c2) {
                #pragma unroll
                for (int nt = 0; nt < 8; ++nt)
                    #pragma unroll
                    for (int r = 0; r < 4; ++r)
                        myT[(quad * 4 + r) * LDZ + nt * 16 + l15] = f2b(s[c2 * 8 + nt][r]);
                #pragma unroll
                for (int ks = 0; ks < 4; ++ks) {
                    bf16x8 a  = *(const bf16x8*)(myT + l15 * LDZ + ks * 32 + quad * 8);
                    bf16x8 b0 = *(const bf16x8*)(vt + (     l15) * LDV + c2 * 128 + ks * 32 + quad * 8);
                    bf16x8 b1 = *(const bf16x8*)(vt + (16 + l15) * LDV + c2 * 128 + ks * 32 + quad * 8);
                    o0 = MFMA16(a, b0, o0);
                    o1 = MFMA16(a, b1, o1);
                }
            }
            // normalize, gate, transpose gw tile (16x32) to A-layout
            #pragma unroll
            for (int r = 0; r < 4; ++r) {
                myT[(quad * 4 + r) * LDZ + l15]      = f2b(o0[r] * inv[r] * ga[it][0][r]);
                myT[(quad * 4 + r) * LDZ + 16 + l15] = f2b(o1[r] * inv[r] * ga[it][1][r]);
            }
            bf16x8 agw = *(const bf16x8*)(myT + l15 * LDZ + quad * 8);
            // rank-32 update into f32 out accumulators
            #pragma unroll
            for (int nt = 0; nt < 8; ++nt) {
                bf16x8 bwo = *(const bf16x8*)(wbuf + (nt * 16 + l15) * LDO + quad * 8);
                oacc[it][nt] = MFMA16(agw, bwo, oacc[it][nt]);
            }
        }
    }

    // ---- epilogue: f32 store, every element of out written ----
    #pragma unroll
    for (int ms = 0; ms < 4; ++ms) {
        #pragma unroll
        for (int nt = 0; nt < 8; ++nt) {
            const int col = nt * 16 + l15;
            const float bb = bo[col];
            #pragma unroll
            for (int r = 0; r < 4; ++r) {
                const size_t row = (size_t)(i * 256 + wave * 64 + ms * 16 + quad * 4 + r);
                out[(row << 7) + col] = oacc[ms][nt][r] + bb;
            }
        }
    }
}

// ---------------------------------------------------------------------------
extern "C" void kernel_launch(void* const* d_in, const int* in_sizes, int n_in,
                              void* d_out, int out_size, void* d_ws, size_t ws_size,
                              hipStream_t stream)
{
    const float* z   = (const float*)d_in[0];
    const float* lns = (const float*)d_in[1];
    const float* lnb = (const float*)d_in[2];
    const float* Wq  = (const float*)d_in[3];
    const float* Wk  = (const float*)d_in[4];
    const float* Wv  = (const float*)d_in[5];
    const float* Wg  = (const float*)d_in[6];
    const float* bg  = (const float*)d_in[7];
    const float* Wo  = (const float*)d_in[8];
    const float* bo  = (const float*)d_in[9];
    float* out = (float*)d_out;

    k_fused<<<256, 256, 0, stream>>>(z, lns, lnb, Wq, Wk, Wv, Wg, bg, Wo, bo, out);
}

// Round 7
// 298.682 us; speedup vs baseline: 1.1495x; 1.1495x over previous
//
#include <hip/hip_runtime.h>

typedef unsigned short u16;
typedef unsigned int   u32;
using bf16x8 = __attribute__((ext_vector_type(8))) __bf16;
using f32x4  = __attribute__((ext_vector_type(4))) float;

#define MFMA16(a,b,c) __builtin_amdgcn_mfma_f32_16x16x32_bf16(a,b,c,0,0,0)

__device__ __forceinline__ float b2f(u16 u){ u32 x = ((u32)u) << 16; return __builtin_bit_cast(float, x); }
__device__ __forceinline__ u16 f2b(float f){
    u32 x = __builtin_bit_cast(u32, f);
    return (u16)((x + 0x7fffu + ((x >> 16) & 1u)) >> 16);
}
__device__ __forceinline__ u32 pk2(float a, float b){ return (u32)f2b(a) | ((u32)f2b(b) << 16); }

// ---------------------------------------------------------------------------
// Fused LN + QKVG proj + row-wise attention + gate + out-proj, FP32 in/out.
// R5-proven structure + register-prefetched weights and dual LDS buffers.
// LN region (17408 B) is reused post-LN as bufA + per-wave transpose tiles.
// One block per row i (grid 256). LDS = 63488 B. 33 barriers total.
// ---------------------------------------------------------------------------
constexpr int LDZ = 136;   // LN per-wave tile stride (272 B) - LN only
constexpr int LDW = 136;   // QKVG slice stride, o-major (272 B)
constexpr int LDO = 40;    // Wo slice stride, n-major (80 B)
constexpr int LDK = 40;    // kh[token][c]
constexpr int LDV = 264;   // vt[c][token] (528 B)
constexpr int LDQ = 40;    // per-wave transpose tile stride (80 B)

__global__ __launch_bounds__(256, 1) void k_fused(
    const float* __restrict__ z, const float* __restrict__ lns, const float* __restrict__ lnb,
    const float* __restrict__ Wq, const float* __restrict__ Wk, const float* __restrict__ Wv,
    const float* __restrict__ Wg, const float* __restrict__ bg,
    const float* __restrict__ Wo, const float* __restrict__ bo,
    float* __restrict__ out)
{
    // regionR: during LN = 4 per-wave 16x136 tiles (17408 B).
    // after LN barrier = bufA[5120 u16] + 4 per-wave 16x40 tiles (15360 B used).
    __shared__ __attribute__((aligned(16))) u16 regionR[8704];   // 17408 B
    __shared__ __attribute__((aligned(16))) u16 kh[256 * LDK];   // 20480 B
    __shared__ __attribute__((aligned(16))) u16 vt[32 * LDV];    // 16896 B
    __shared__ __attribute__((aligned(16))) u16 bufB[32 * LDW];  //  8704 B  = 63488

    const int i = blockIdx.x;
    const int t = threadIdx.x;
    const int lane = t & 63;
    const int l15  = lane & 15;
    const int quad = lane >> 4;
    const int wave = t >> 6;

    u16* __restrict__ lntile = regionR + wave * 16 * LDZ;          // LN phase only
    u16* __restrict__ bufA   = regionR;                            // 5120 u16
    u16* __restrict__ myT    = regionR + 5120 + wave * 16 * LDQ;   // 640 u16/wave

    float4 wregA[4], wregB[4];
    // prefetch a QKVG head-slice into regs: c = t*4 + k2*1024
    auto prefW = [&](const float* __restrict__ W, int h, float4 (&r)[4]) {
        #pragma unroll
        for (int k2 = 0; k2 < 4; ++k2) {
            const int c = t * 4 + k2 * 1024;
            r[k2] = *(const float4*)(W + (c >> 5) * 128 + h * 32 + (c & 31));
        }
    };
    auto prefWoF = [&](int h, float4 (&r)[4]) {
        #pragma unroll
        for (int k2 = 0; k2 < 4; ++k2)
            r[k2] = *(const float4*)(Wo + h * 4096 + t * 4 + k2 * 1024);
    };
    // stage hi: buf[o][e] = bf16(W[e][h*32+o])  (same contents as R5's stageWh)
    auto stageHi = [&](u16* __restrict__ buf, const float4 (&r)[4]) {
        #pragma unroll
        for (int k2 = 0; k2 < 4; ++k2) {
            const int c = t * 4 + k2 * 1024;
            const int e = c >> 5, o = c & 31;
            buf[(o    ) * LDW + e] = f2b(r[k2].x);
            buf[(o + 1) * LDW + e] = f2b(r[k2].y);
            buf[(o + 2) * LDW + e] = f2b(r[k2].z);
            buf[(o + 3) * LDW + e] = f2b(r[k2].w);
        }
    };
    // stage lo residual (same contents as R5's stageWl)
    auto stageLo = [&](u16* __restrict__ buf, const float4 (&r)[4]) {
        #pragma unroll
        for (int k2 = 0; k2 < 4; ++k2) {
            const int c = t * 4 + k2 * 1024;
            const int e = c >> 5, o = c & 31;
            const float v0 = r[k2].x, v1 = r[k2].y, v2 = r[k2].z, v3 = r[k2].w;
            buf[(o    ) * LDW + e] = f2b(v0 - b2f(f2b(v0)));
            buf[(o + 1) * LDW + e] = f2b(v1 - b2f(f2b(v1)));
            buf[(o + 2) * LDW + e] = f2b(v2 - b2f(f2b(v2)));
            buf[(o + 3) * LDW + e] = f2b(v3 - b2f(f2b(v3)));
        }
    };
    // stage Wo: bufA[n][k] = bf16(Wo[h*32+k][n])  (same contents as R5's stageWoS)
    auto stageWoL = [&](const float4 (&r)[4]) {
        #pragma unroll
        for (int k2 = 0; k2 < 4; ++k2) {
            const int c = t * 4 + k2 * 1024;
            const int kk = c >> 7, n = c & 127;
            bufA[(n    ) * LDO + kk] = f2b(r[k2].x);
            bufA[(n + 1) * LDO + kk] = f2b(r[k2].y);
            bufA[(n + 2) * LDO + kk] = f2b(r[k2].z);
            bufA[(n + 3) * LDO + kk] = f2b(r[k2].w);
        }
    };

    prefW(Wq, 0, wregA);     // overlap with LN

    // ---- per-wave LayerNorm (exact f32) -> hi/lo A-frags (R5 verbatim) ----
    bf16x8 zfh[4][4], zfl[4][4];
    {
        float sc[32], bi[32];
        #pragma unroll
        for (int u = 0; u < 8; ++u) {
            float4 s4 = *(const float4*)(lns + quad * 32 + u * 4);
            float4 b4 = *(const float4*)(lnb + quad * 32 + u * 4);
            sc[u*4+0]=s4.x; sc[u*4+1]=s4.y; sc[u*4+2]=s4.z; sc[u*4+3]=s4.w;
            bi[u*4+0]=b4.x; bi[u*4+1]=b4.y; bi[u*4+2]=b4.z; bi[u*4+3]=b4.w;
        }
        #pragma unroll 1
        for (int ms = 0; ms < 4; ++ms) {
            const size_t tok = (size_t)(i * 256 + wave * 64 + ms * 16 + l15);
            float x[32];
            #pragma unroll
            for (int u = 0; u < 8; ++u) {
                float4 v4 = *(const float4*)(z + (tok << 7) + quad * 32 + u * 4);
                x[u*4+0]=v4.x; x[u*4+1]=v4.y; x[u*4+2]=v4.z; x[u*4+3]=v4.w;
            }
            float s = 0.f;
            #pragma unroll
            for (int k = 0; k < 32; ++k) s += x[k];
            s += __shfl_xor(s, 16, 64); s += __shfl_xor(s, 32, 64);
            const float mu = s * 0.0078125f;
            float vs = 0.f;
            #pragma unroll
            for (int k = 0; k < 32; ++k) { float d = x[k] - mu; vs += d * d; }
            vs += __shfl_xor(vs, 16, 64); vs += __shfl_xor(vs, 32, 64);
            const float rs = rsqrtf(vs * 0.0078125f + 1e-5f);
            float y[32];
            #pragma unroll
            for (int k = 0; k < 32; ++k) y[k] = (x[k] - mu) * rs * sc[k] + bi[k];
            // hi tile -> frags
            #pragma unroll
            for (int u = 0; u < 4; ++u) {
                uint4 o;
                o.x = pk2(y[u*8+0], y[u*8+1]); o.y = pk2(y[u*8+2], y[u*8+3]);
                o.z = pk2(y[u*8+4], y[u*8+5]); o.w = pk2(y[u*8+6], y[u*8+7]);
                *(uint4*)(lntile + l15 * LDZ + quad * 32 + u * 8) = o;
            }
            #pragma unroll
            for (int ks = 0; ks < 4; ++ks)
                zfh[ms][ks] = *(const bf16x8*)(lntile + l15 * LDZ + ks * 32 + quad * 8);
            // lo residual tile -> frags
            #pragma unroll
            for (int k = 0; k < 32; ++k) y[k] -= b2f(f2b(y[k]));
            #pragma unroll
            for (int u = 0; u < 4; ++u) {
                uint4 o;
                o.x = pk2(y[u*8+0], y[u*8+1]); o.y = pk2(y[u*8+2], y[u*8+3]);
                o.z = pk2(y[u*8+4], y[u*8+5]); o.w = pk2(y[u*8+6], y[u*8+7]);
                *(uint4*)(lntile + l15 * LDZ + quad * 32 + u * 8) = o;
            }
            #pragma unroll
            for (int ks = 0; ks < 4; ++ks)
                zfl[ms][ks] = *(const bf16x8*)(lntile + l15 * LDZ + ks * 32 + quad * 8);
        }
    }
    __syncthreads();   // LN tiles dead; regionR becomes bufA + transpose tiles

    // GEMM accumulate (R5's gemmAcc body, buffer-parametrized)
    auto gemmAcc = [&](f32x4 (&acc)[4][2], bf16x8 (&af)[4][4], const u16* __restrict__ buf) {
        #pragma unroll
        for (int ms = 0; ms < 4; ++ms)
            #pragma unroll
            for (int nt = 0; nt < 2; ++nt) {
                f32x4 ac = acc[ms][nt];
                #pragma unroll
                for (int ks = 0; ks < 4; ++ks) {
                    bf16x8 b = *(const bf16x8*)(buf + (nt * 16 + l15) * LDW + ks * 32 + quad * 8);
                    ac = MFMA16(af[ms][ks], b, ac);
                }
                acc[ms][nt] = ac;
            }
    };
    auto zero42 = [](f32x4 (&a)[4][2]) {
        #pragma unroll
        for (int ms = 0; ms < 4; ++ms)
            #pragma unroll
            for (int nt = 0; nt < 2; ++nt) a[ms][nt] = f32x4{0.f,0.f,0.f,0.f};
    };

    bf16x8 aq[4];
    f32x4  ga[4][2];
    f32x4  oacc[4][8];
    #pragma unroll
    for (int ms = 0; ms < 4; ++ms)
        #pragma unroll
        for (int nt = 0; nt < 8; ++nt)
            oacc[ms][nt] = f32x4{0.f, 0.f, 0.f, 0.f};

    #pragma unroll 1
    for (int h = 0; h < 4; ++h) {
        // ---- S1: Q (hi->bufA, lo->bufB from the same regs) ----
        stageHi(bufA, wregA); stageLo(bufB, wregA);
        __syncthreads();
        prefW(Wk, h, wregA);
        {
            f32x4 qa[4][2]; zero42(qa);
            gemmAcc(qa, zfh, bufA); gemmAcc(qa, zfl, bufA); gemmAcc(qa, zfh, bufB);
            #pragma unroll
            for (int ms = 0; ms < 4; ++ms) {
                #pragma unroll
                for (int nt = 0; nt < 2; ++nt)
                    #pragma unroll
                    for (int r = 0; r < 4; ++r)
                        myT[(quad * 4 + r) * LDQ + nt * 16 + l15] = f2b(qa[ms][nt][r]);
                aq[ms] = *(const bf16x8*)(myT + l15 * LDQ + quad * 8);  // same-wave round-trip
            }
        }
        __syncthreads();
        // ---- S2: K ----
        stageHi(bufA, wregA); stageLo(bufB, wregA);
        __syncthreads();
        prefW(Wv, h, wregA); prefW(Wg, h, wregB);
        {
            f32x4 ka[4][2]; zero42(ka);
            gemmAcc(ka, zfh, bufA); gemmAcc(ka, zfl, bufA); gemmAcc(ka, zfh, bufB);
            #pragma unroll
            for (int ms = 0; ms < 4; ++ms)
                #pragma unroll
                for (int nt = 0; nt < 2; ++nt)
                    #pragma unroll
                    for (int r = 0; r < 4; ++r)
                        kh[(wave * 64 + ms * 16 + quad * 4 + r) * LDK + nt * 16 + l15] = f2b(ka[ms][nt][r]);
        }
        __syncthreads();
        // ---- S3: V -> bufA, G -> bufB (hi only) ----
        stageHi(bufA, wregA); stageHi(bufB, wregB);
        __syncthreads();
        prefWoF(h, wregA);
        {
            f32x4 va[4][2]; zero42(va); gemmAcc(va, zfh, bufA);
            #pragma unroll
            for (int ms = 0; ms < 4; ++ms)
                #pragma unroll
                for (int nt = 0; nt < 2; ++nt)
                    #pragma unroll
                    for (int r = 0; r < 4; ++r)
                        vt[(nt * 16 + l15) * LDV + wave * 64 + ms * 16 + quad * 4 + r] = f2b(va[ms][nt][r]);
            zero42(ga); gemmAcc(ga, zfh, bufB);
            #pragma unroll
            for (int nt = 0; nt < 2; ++nt) {
                const float bb = bg[h * 32 + nt * 16 + l15];
                #pragma unroll
                for (int ms = 0; ms < 4; ++ms)
                    #pragma unroll
                    for (int r = 0; r < 4; ++r)
                        ga[ms][nt][r] = 1.f / (1.f + __expf(-(ga[ms][nt][r] + bb)));
            }
        }
        __syncthreads();
        // ---- S4: Wo -> bufA, then attention + out-proj ----
        stageWoL(wregA);
        __syncthreads();
        if (h < 3) prefW(Wq, h + 1, wregA);

        #pragma unroll 1
        for (int it = 0; it < 4; ++it) {
            f32x4 s[16];
            #pragma unroll
            for (int nt = 0; nt < 16; ++nt) {
                bf16x8 b = *(const bf16x8*)(kh + (nt * 16 + l15) * LDK + quad * 8);
                f32x4 zacc = {0.f, 0.f, 0.f, 0.f};
                s[nt] = MFMA16(aq[it], b, zacc);
            }
            float inv[4];
            #pragma unroll
            for (int r = 0; r < 4; ++r) {
                float mx = s[0][r];
                #pragma unroll
                for (int nt = 1; nt < 16; ++nt) mx = fmaxf(mx, s[nt][r]);
                #pragma unroll
                for (int m = 1; m < 16; m <<= 1) mx = fmaxf(mx, __shfl_xor(mx, m, 64));
                float sm = 0.f;
                #pragma unroll
                for (int nt = 0; nt < 16; ++nt) {
                    float e = __expf(s[nt][r] - mx);
                    s[nt][r] = e; sm += e;
                }
                #pragma unroll
                for (int m = 1; m < 16; m <<= 1) sm += __shfl_xor(sm, m, 64);
                inv[r] = 1.f / sm;
            }
            // PV in eight 32-col chunks through the 16x40 per-wave tile
            f32x4 o0 = {0.f,0.f,0.f,0.f}, o1 = {0.f,0.f,0.f,0.f};
            #pragma unroll
            for (int c8 = 0; c8 < 8; ++c8) {
                #pragma unroll
                for (int n2 = 0; n2 < 2; ++n2)
                    #pragma unroll
                    for (int r = 0; r < 4; ++r)
                        myT[(quad * 4 + r) * LDQ + n2 * 16 + l15] = f2b(s[c8 * 2 + n2][r]);
                bf16x8 a  = *(const bf16x8*)(myT + l15 * LDQ + quad * 8);
                bf16x8 b0 = *(const bf16x8*)(vt + (     l15) * LDV + c8 * 32 + quad * 8);
                bf16x8 b1 = *(const bf16x8*)(vt + (16 + l15) * LDV + c8 * 32 + quad * 8);
                o0 = MFMA16(a, b0, o0);
                o1 = MFMA16(a, b1, o1);
            }
            // gate, transpose 16x32 gw tile to A-layout, rank-32 out-proj update
            #pragma unroll
            for (int r = 0; r < 4; ++r) {
                myT[(quad * 4 + r) * LDQ + l15]      = f2b(o0[r] * inv[r] * ga[it][0][r]);
                myT[(quad * 4 + r) * LDQ + 16 + l15] = f2b(o1[r] * inv[r] * ga[it][1][r]);
            }
            bf16x8 agw = *(const bf16x8*)(myT + l15 * LDQ + quad * 8);
            #pragma unroll
            for (int nt = 0; nt < 8; ++nt) {
                bf16x8 bwo = *(const bf16x8*)(bufA + (nt * 16 + l15) * LDO + quad * 8);
                oacc[it][nt] = MFMA16(agw, bwo, oacc[it][nt]);
            }
        }
        __syncthreads();
    }

    // ---- epilogue: f32 store ----
    #pragma unroll
    for (int ms = 0; ms < 4; ++ms) {
        #pragma unroll
        for (int nt = 0; nt < 8; ++nt) {
            const int col = nt * 16 + l15;
            const float bb = bo[col];
            #pragma unroll
            for (int r = 0; r < 4; ++r) {
                const size_t row = (size_t)(i * 256 + wave * 64 + ms * 16 + quad * 4 + r);
                out[(row << 7) + col] = oacc[ms][nt][r] + bb;
            }
        }
    }
}

// ---------------------------------------------------------------------------
extern "C" void kernel_launch(void* const* d_in, const int* in_sizes, int n_in,
                              void* d_out, int out_size, void* d_ws, size_t ws_size,
                              hipStream_t stream)
{
    const float* z   = (const float*)d_in[0];
    const float* lns = (const float*)d_in[1];
    const float* lnb = (const float*)d_in[2];
    const float* Wq  = (const float*)d_in[3];
    const float* Wk  = (const float*)d_in[4];
    const float* Wv  = (const float*)d_in[5];
    const float* Wg  = (const float*)d_in[6];
    const float* bg  = (const float*)d_in[7];
    const float* Wo  = (const float*)d_in[8];
    const float* bo  = (const float*)d_in[9];
    float* out = (float*)d_out;

    k_fused<<<256, 256, 0, stream>>>(z, lns, lnb, Wq, Wk, Wv, Wg, bg, Wo, bo, out);
}

// Round 8
// 240.255 us; speedup vs baseline: 1.4290x; 1.2432x over previous
//
#include <hip/hip_runtime.h>

typedef unsigned short u16;
typedef unsigned int   u32;
using bf16x8 = __attribute__((ext_vector_type(8))) __bf16;
using f32x4  = __attribute__((ext_vector_type(4))) float;

#define MFMA16(a,b,c) __builtin_amdgcn_mfma_f32_16x16x32_bf16(a,b,c,0,0,0)

__device__ __forceinline__ float b2f(u16 u){ u32 x = ((u32)u) << 16; return __builtin_bit_cast(float, x); }
__device__ __forceinline__ u16 f2b(float f){
    u32 x = __builtin_bit_cast(u32, f);
    return (u16)((x + 0x7fffu + ((x >> 16) & 1u)) >> 16);
}
__device__ __forceinline__ u32 pk2(float a, float b){ return (u32)f2b(a) | ((u32)f2b(b) << 16); }

// ---------------------------------------------------------------------------
// Fused LN + QKVG proj + row-wise attention + gate + out-proj, FP32 in/out.
// 512 threads (8 waves) per block, one block per row i (grid 256) ->
// 2 waves/SIMD for latency hiding. Each wave owns 32 tokens (2 m-tiles).
// LN tiles alias the kh/vt region (dead during LN). LDS pool = 66560 B.
// ---------------------------------------------------------------------------
constexpr int LDZ = 136;   // LN per-wave tile stride (272 B) - LN phase only
constexpr int LDW = 136;   // QKVG slice stride, o-major (272 B)
constexpr int LDO = 40;    // Wo slice stride, n-major (80 B)
constexpr int LDK = 40;    // kh[token][c] (80 B rows)
constexpr int LDV = 264;   // vt[c][token] (528 B rows)
constexpr int LDQ = 40;    // per-wave transpose tile stride (80 B)

// u16 offsets into the pool (total 33280 u16 = 66560 B):
//   kh   [    0 .. 10240)   256*40
//   vt   [10240 .. 18688)   32*264
//   bufA [18688 .. 23808)   5120 (QKVG-hi 32xLDW | Wo 128xLDO)
//   myT  [23808 .. 28928)   8 waves * 16*40
//   bufB [28928 .. 33280)   32*LDW (QKVG-lo / G)
// LN phase: per-wave 16x136 tiles at [wave*2176], total 17408 u16 -> aliases kh+vt.

__global__ __launch_bounds__(512, 2) void k_fused(
    const float* __restrict__ z, const float* __restrict__ lns, const float* __restrict__ lnb,
    const float* __restrict__ Wq, const float* __restrict__ Wk, const float* __restrict__ Wv,
    const float* __restrict__ Wg, const float* __restrict__ bg,
    const float* __restrict__ Wo, const float* __restrict__ bo,
    float* __restrict__ out)
{
    __shared__ __attribute__((aligned(16))) u16 smem[33280];   // 66560 B

    const int i = blockIdx.x;
    const int t = threadIdx.x;
    const int lane = t & 63;
    const int l15  = lane & 15;
    const int quad = lane >> 4;
    const int wave = t >> 6;           // 0..7

    u16* __restrict__ kh   = smem;
    u16* __restrict__ vt   = smem + 10240;
    u16* __restrict__ bufA = smem + 18688;
    u16* __restrict__ myT  = smem + 23808 + wave * 16 * LDQ;
    u16* __restrict__ bufB = smem + 28928;
    u16* __restrict__ lntile = smem + wave * 16 * LDZ;   // LN phase only

    float4 wregA[2], wregB[2];
    // prefetch a QKVG head-slice into regs: c = t*4 + k2*2048 covers 4096
    auto prefW = [&](const float* __restrict__ W, int h, float4 (&r)[2]) {
        #pragma unroll
        for (int k2 = 0; k2 < 2; ++k2) {
            const int c = t * 4 + k2 * 2048;
            r[k2] = *(const float4*)(W + (c >> 5) * 128 + h * 32 + (c & 31));
        }
    };
    auto prefWoF = [&](int h, float4 (&r)[2]) {
        #pragma unroll
        for (int k2 = 0; k2 < 2; ++k2)
            r[k2] = *(const float4*)(Wo + h * 4096 + t * 4 + k2 * 2048);
    };
    auto stageHi = [&](u16* __restrict__ buf, const float4 (&r)[2]) {
        #pragma unroll
        for (int k2 = 0; k2 < 2; ++k2) {
            const int c = t * 4 + k2 * 2048;
            const int e = c >> 5, o = c & 31;
            buf[(o    ) * LDW + e] = f2b(r[k2].x);
            buf[(o + 1) * LDW + e] = f2b(r[k2].y);
            buf[(o + 2) * LDW + e] = f2b(r[k2].z);
            buf[(o + 3) * LDW + e] = f2b(r[k2].w);
        }
    };
    auto stageLo = [&](u16* __restrict__ buf, const float4 (&r)[2]) {
        #pragma unroll
        for (int k2 = 0; k2 < 2; ++k2) {
            const int c = t * 4 + k2 * 2048;
            const int e = c >> 5, o = c & 31;
            const float v0 = r[k2].x, v1 = r[k2].y, v2 = r[k2].z, v3 = r[k2].w;
            buf[(o    ) * LDW + e] = f2b(v0 - b2f(f2b(v0)));
            buf[(o + 1) * LDW + e] = f2b(v1 - b2f(f2b(v1)));
            buf[(o + 2) * LDW + e] = f2b(v2 - b2f(f2b(v2)));
            buf[(o + 3) * LDW + e] = f2b(v3 - b2f(f2b(v3)));
        }
    };
    auto stageWoL = [&](const float4 (&r)[2]) {
        #pragma unroll
        for (int k2 = 0; k2 < 2; ++k2) {
            const int c = t * 4 + k2 * 2048;
            const int kk = c >> 7, n = c & 127;
            bufA[(n    ) * LDO + kk] = f2b(r[k2].x);
            bufA[(n + 1) * LDO + kk] = f2b(r[k2].y);
            bufA[(n + 2) * LDO + kk] = f2b(r[k2].z);
            bufA[(n + 3) * LDO + kk] = f2b(r[k2].w);
        }
    };

    prefW(Wq, 0, wregA);     // overlap with LN

    // ---- per-wave LayerNorm (exact f32) -> hi/lo A-frags, 2 m-tiles/wave ----
    bf16x8 zfh[2][4], zfl[2][4];
    {
        float sc[32], bi[32];
        #pragma unroll
        for (int u = 0; u < 8; ++u) {
            float4 s4 = *(const float4*)(lns + quad * 32 + u * 4);
            float4 b4 = *(const float4*)(lnb + quad * 32 + u * 4);
            sc[u*4+0]=s4.x; sc[u*4+1]=s4.y; sc[u*4+2]=s4.z; sc[u*4+3]=s4.w;
            bi[u*4+0]=b4.x; bi[u*4+1]=b4.y; bi[u*4+2]=b4.z; bi[u*4+3]=b4.w;
        }
        #pragma unroll 1
        for (int ms = 0; ms < 2; ++ms) {
            const size_t tok = (size_t)(i * 256 + wave * 32 + ms * 16 + l15);
            float x[32];
            #pragma unroll
            for (int u = 0; u < 8; ++u) {
                float4 v4 = *(const float4*)(z + (tok << 7) + quad * 32 + u * 4);
                x[u*4+0]=v4.x; x[u*4+1]=v4.y; x[u*4+2]=v4.z; x[u*4+3]=v4.w;
            }
            float s = 0.f;
            #pragma unroll
            for (int k = 0; k < 32; ++k) s += x[k];
            s += __shfl_xor(s, 16, 64); s += __shfl_xor(s, 32, 64);
            const float mu = s * 0.0078125f;
            float vs = 0.f;
            #pragma unroll
            for (int k = 0; k < 32; ++k) { float d = x[k] - mu; vs += d * d; }
            vs += __shfl_xor(vs, 16, 64); vs += __shfl_xor(vs, 32, 64);
            const float rs = rsqrtf(vs * 0.0078125f + 1e-5f);
            float y[32];
            #pragma unroll
            for (int k = 0; k < 32; ++k) y[k] = (x[k] - mu) * rs * sc[k] + bi[k];
            // hi tile -> frags
            #pragma unroll
            for (int u = 0; u < 4; ++u) {
                uint4 o;
                o.x = pk2(y[u*8+0], y[u*8+1]); o.y = pk2(y[u*8+2], y[u*8+3]);
                o.z = pk2(y[u*8+4], y[u*8+5]); o.w = pk2(y[u*8+6], y[u*8+7]);
                *(uint4*)(lntile + l15 * LDZ + quad * 32 + u * 8) = o;
            }
            #pragma unroll
            for (int ks = 0; ks < 4; ++ks)
                zfh[ms][ks] = *(const bf16x8*)(lntile + l15 * LDZ + ks * 32 + quad * 8);
            // lo residual tile -> frags
            #pragma unroll
            for (int k = 0; k < 32; ++k) y[k] -= b2f(f2b(y[k]));
            #pragma unroll
            for (int u = 0; u < 4; ++u) {
                uint4 o;
                o.x = pk2(y[u*8+0], y[u*8+1]); o.y = pk2(y[u*8+2], y[u*8+3]);
                o.z = pk2(y[u*8+4], y[u*8+5]); o.w = pk2(y[u*8+6], y[u*8+7]);
                *(uint4*)(lntile + l15 * LDZ + quad * 32 + u * 8) = o;
            }
            #pragma unroll
            for (int ks = 0; ks < 4; ++ks)
                zfl[ms][ks] = *(const bf16x8*)(lntile + l15 * LDZ + ks * 32 + quad * 8);
        }
    }
    __syncthreads();   // LN tiles dead; region becomes kh/vt

    auto gemmAcc = [&](f32x4 (&acc)[2][2], bf16x8 (&af)[2][4], const u16* __restrict__ buf) {
        #pragma unroll
        for (int ms = 0; ms < 2; ++ms)
            #pragma unroll
            for (int nt = 0; nt < 2; ++nt) {
                f32x4 ac = acc[ms][nt];
                #pragma unroll
                for (int ks = 0; ks < 4; ++ks) {
                    bf16x8 b = *(const bf16x8*)(buf + (nt * 16 + l15) * LDW + ks * 32 + quad * 8);
                    ac = MFMA16(af[ms][ks], b, ac);
                }
                acc[ms][nt] = ac;
            }
    };
    auto zero22 = [](f32x4 (&a)[2][2]) {
        #pragma unroll
        for (int ms = 0; ms < 2; ++ms)
            #pragma unroll
            for (int nt = 0; nt < 2; ++nt) a[ms][nt] = f32x4{0.f,0.f,0.f,0.f};
    };

    bf16x8 aq[2];
    f32x4  ga[2][2];
    f32x4  oacc[2][8];
    #pragma unroll
    for (int ms = 0; ms < 2; ++ms)
        #pragma unroll
        for (int nt = 0; nt < 8; ++nt)
            oacc[ms][nt] = f32x4{0.f, 0.f, 0.f, 0.f};

    #pragma unroll 1
    for (int h = 0; h < 4; ++h) {
        // ---- S1: Q (hi->bufA, lo->bufB from the same regs) ----
        stageHi(bufA, wregA); stageLo(bufB, wregA);
        __syncthreads();
        prefW(Wk, h, wregA);
        {
            f32x4 qa[2][2]; zero22(qa);
            gemmAcc(qa, zfh, bufA); gemmAcc(qa, zfl, bufA); gemmAcc(qa, zfh, bufB);
            #pragma unroll
            for (int ms = 0; ms < 2; ++ms) {
                #pragma unroll
                for (int nt = 0; nt < 2; ++nt)
                    #pragma unroll
                    for (int r = 0; r < 4; ++r)
                        myT[(quad * 4 + r) * LDQ + nt * 16 + l15] = f2b(qa[ms][nt][r]);
                aq[ms] = *(const bf16x8*)(myT + l15 * LDQ + quad * 8);  // same-wave round-trip
            }
        }
        __syncthreads();
        // ---- S2: K ----
        stageHi(bufA, wregA); stageLo(bufB, wregA);
        __syncthreads();
        prefW(Wv, h, wregA); prefW(Wg, h, wregB);
        {
            f32x4 ka[2][2]; zero22(ka);
            gemmAcc(ka, zfh, bufA); gemmAcc(ka, zfl, bufA); gemmAcc(ka, zfh, bufB);
            #pragma unroll
            for (int ms = 0; ms < 2; ++ms)
                #pragma unroll
                for (int nt = 0; nt < 2; ++nt)
                    #pragma unroll
                    for (int r = 0; r < 4; ++r)
                        kh[(wave * 32 + ms * 16 + quad * 4 + r) * LDK + nt * 16 + l15] = f2b(ka[ms][nt][r]);
        }
        __syncthreads();
        // ---- S3: V -> bufA, G -> bufB (hi only) ----
        stageHi(bufA, wregA); stageHi(bufB, wregB);
        __syncthreads();
        prefWoF(h, wregA);
        {
            f32x4 va[2][2]; zero22(va); gemmAcc(va, zfh, bufA);
            #pragma unroll
            for (int ms = 0; ms < 2; ++ms)
                #pragma unroll
                for (int nt = 0; nt < 2; ++nt)
                    #pragma unroll
                    for (int r = 0; r < 4; ++r)
                        vt[(nt * 16 + l15) * LDV + wave * 32 + ms * 16 + quad * 4 + r] = f2b(va[ms][nt][r]);
            zero22(ga); gemmAcc(ga, zfh, bufB);
            #pragma unroll
            for (int nt = 0; nt < 2; ++nt) {
                const float bb = bg[h * 32 + nt * 16 + l15];
                #pragma unroll
                for (int ms = 0; ms < 2; ++ms)
                    #pragma unroll
                    for (int r = 0; r < 4; ++r)
                        ga[ms][nt][r] = 1.f / (1.f + __expf(-(ga[ms][nt][r] + bb)));
            }
        }
        __syncthreads();
        // ---- S4: Wo -> bufA, then attention + out-proj ----
        stageWoL(wregA);
        __syncthreads();
        if (h < 3) prefW(Wq, h + 1, wregA);

        #pragma unroll 1
        for (int it = 0; it < 2; ++it) {
            f32x4 s[16];
            #pragma unroll
            for (int nt = 0; nt < 16; ++nt) {
                bf16x8 b = *(const bf16x8*)(kh + (nt * 16 + l15) * LDK + quad * 8);
                f32x4 zacc = {0.f, 0.f, 0.f, 0.f};
                s[nt] = MFMA16(aq[it], b, zacc);
            }
            float inv[4];
            #pragma unroll
            for (int r = 0; r < 4; ++r) {
                float mx = s[0][r];
                #pragma unroll
                for (int nt = 1; nt < 16; ++nt) mx = fmaxf(mx, s[nt][r]);
                #pragma unroll
                for (int m = 1; m < 16; m <<= 1) mx = fmaxf(mx, __shfl_xor(mx, m, 64));
                float sm = 0.f;
                #pragma unroll
                for (int nt = 0; nt < 16; ++nt) {
                    float e = __expf(s[nt][r] - mx);
                    s[nt][r] = e; sm += e;
                }
                #pragma unroll
                for (int m = 1; m < 16; m <<= 1) sm += __shfl_xor(sm, m, 64);
                inv[r] = 1.f / sm;
            }
            // PV in eight 32-col chunks through the 16x40 per-wave tile
            f32x4 o0 = {0.f,0.f,0.f,0.f}, o1 = {0.f,0.f,0.f,0.f};
            #pragma unroll
            for (int c8 = 0; c8 < 8; ++c8) {
                #pragma unroll
                for (int n2 = 0; n2 < 2; ++n2)
                    #pragma unroll
                    for (int r = 0; r < 4; ++r)
                        myT[(quad * 4 + r) * LDQ + n2 * 16 + l15] = f2b(s[c8 * 2 + n2][r]);
                bf16x8 a  = *(const bf16x8*)(myT + l15 * LDQ + quad * 8);
                bf16x8 b0 = *(const bf16x8*)(vt + (     l15) * LDV + c8 * 32 + quad * 8);
                bf16x8 b1 = *(const bf16x8*)(vt + (16 + l15) * LDV + c8 * 32 + quad * 8);
                o0 = MFMA16(a, b0, o0);
                o1 = MFMA16(a, b1, o1);
            }
            // gate, transpose 16x32 gw tile to A-layout, rank-32 out-proj update
            #pragma unroll
            for (int r = 0; r < 4; ++r) {
                myT[(quad * 4 + r) * LDQ + l15]      = f2b(o0[r] * inv[r] * ga[it][0][r]);
                myT[(quad * 4 + r) * LDQ + 16 + l15] = f2b(o1[r] * inv[r] * ga[it][1][r]);
            }
            bf16x8 agw = *(const bf16x8*)(myT + l15 * LDQ + quad * 8);
            #pragma unroll
            for (int nt = 0; nt < 8; ++nt) {
                bf16x8 bwo = *(const bf16x8*)(bufA + (nt * 16 + l15) * LDO + quad * 8);
                oacc[it][nt] = MFMA16(agw, bwo, oacc[it][nt]);
            }
        }
        __syncthreads();
    }

    // ---- epilogue: f32 store ----
    #pragma unroll
    for (int ms = 0; ms < 2; ++ms) {
        #pragma unroll
        for (int nt = 0; nt < 8; ++nt) {
            const int col = nt * 16 + l15;
            const float bb = bo[col];
            #pragma unroll
            for (int r = 0; r < 4; ++r) {
                const size_t row = (size_t)(i * 256 + wave * 32 + ms * 16 + quad * 4 + r);
                out[(row << 7) + col] = oacc[ms][nt][r] + bb;
            }
        }
    }
}

// ---------------------------------------------------------------------------
extern "C" void kernel_launch(void* const* d_in, const int* in_sizes, int n_in,
                              void* d_out, int out_size, void* d_ws, size_t ws_size,
                              hipStream_t stream)
{
    const float* z   = (const float*)d_in[0];
    const float* lns = (const float*)d_in[1];
    const float* lnb = (const float*)d_in[2];
    const float* Wq  = (const float*)d_in[3];
    const float* Wk  = (const float*)d_in[4];
    const float* Wv  = (const float*)d_in[5];
    const float* Wg  = (const float*)d_in[6];
    const float* bg  = (const float*)d_in[7];
    const float* Wo  = (const float*)d_in[8];
    const float* bo  = (const float*)d_in[9];
    float* out = (float*)d_out;

    k_fused<<<256, 512, 0, stream>>>(z, lns, lnb, Wq, Wk, Wv, Wg, bg, Wo, bo, out);
}

// Round 9
// 233.357 us; speedup vs baseline: 1.4712x; 1.0296x over previous
//
#include <hip/hip_runtime.h>

typedef unsigned short u16;
typedef unsigned int   u32;
using bf16x8 = __attribute__((ext_vector_type(8))) __bf16;
using f32x4  = __attribute__((ext_vector_type(4))) float;

#define MFMA16(a,b,c) __builtin_amdgcn_mfma_f32_16x16x32_bf16(a,b,c,0,0,0)

__device__ __forceinline__ float b2f(u16 u){ u32 x = ((u32)u) << 16; return __builtin_bit_cast(float, x); }
__device__ __forceinline__ u16 f2b(float f){
    u32 x = __builtin_bit_cast(u32, f);
    return (u16)((x + 0x7fffu + ((x >> 16) & 1u)) >> 16);
}
__device__ __forceinline__ u32 pk2(float a, float b){ return (u32)f2b(a) | ((u32)f2b(b) << 16); }

constexpr int LDB = 136;   // B-frag staging stride (o-major) for K1/K3
constexpr int LDK = 40;    // kh[token][c]
constexpr int LDV = 264;   // vt[c][token]
constexpr int LDQ = 40;    // per-wave transpose tile
constexpr int LDZ = 136;   // LN tile stride

// ===========================================================================
// K1: LN + Q/K/V/G projections. Grid 512 x 512thr (8 waves, 16 rows/wave).
// Q,K: 3-pass hi/lo (zn-hi*W-hi + zn-lo*W-hi + zn-hi*W-lo). V: 1-pass.
// G: 1-pass + bias + sigmoid. Row-major bf16 outputs to workspace.
// LDS: bufH(34816B) + bufL(34816B) = 69632 B -> 2 blocks/CU.
// ===========================================================================
__global__ __launch_bounds__(512, 2) void k1_proj(
    const float* __restrict__ z, const float* __restrict__ lns, const float* __restrict__ lnb,
    const float* __restrict__ Wq, const float* __restrict__ Wk, const float* __restrict__ Wv,
    const float* __restrict__ Wg, const float* __restrict__ bg,
    u16* __restrict__ Qo, u16* __restrict__ Ko, u16* __restrict__ Vo, u16* __restrict__ Go)
{
    __shared__ __attribute__((aligned(16))) u16 bufH[128 * LDB];  // 34816 B
    __shared__ __attribute__((aligned(16))) u16 bufL[128 * LDB];  // 34816 B

    const int t = threadIdx.x;
    const int lane = t & 63;
    const int l15  = lane & 15;
    const int quad = lane >> 4;
    const int wave = t >> 6;
    const int rowbase = blockIdx.x * 128 + wave * 16;
    u16* __restrict__ lntile = bufH + wave * 16 * LDZ;   // LN phase only

    // ---- per-wave LayerNorm (exact f32) -> hi/lo A-frags (R8-proven) ----
    bf16x8 zfh[4], zfl[4];
    {
        float sc[32], bi[32];
        #pragma unroll
        for (int u = 0; u < 8; ++u) {
            float4 s4 = *(const float4*)(lns + quad * 32 + u * 4);
            float4 b4 = *(const float4*)(lnb + quad * 32 + u * 4);
            sc[u*4+0]=s4.x; sc[u*4+1]=s4.y; sc[u*4+2]=s4.z; sc[u*4+3]=s4.w;
            bi[u*4+0]=b4.x; bi[u*4+1]=b4.y; bi[u*4+2]=b4.z; bi[u*4+3]=b4.w;
        }
        const size_t tok = (size_t)(rowbase + l15);
        float x[32];
        #pragma unroll
        for (int u = 0; u < 8; ++u) {
            float4 v4 = *(const float4*)(z + (tok << 7) + quad * 32 + u * 4);
            x[u*4+0]=v4.x; x[u*4+1]=v4.y; x[u*4+2]=v4.z; x[u*4+3]=v4.w;
        }
        float s = 0.f;
        #pragma unroll
        for (int k = 0; k < 32; ++k) s += x[k];
        s += __shfl_xor(s, 16, 64); s += __shfl_xor(s, 32, 64);
        const float mu = s * 0.0078125f;
        float vs = 0.f;
        #pragma unroll
        for (int k = 0; k < 32; ++k) { float d = x[k] - mu; vs += d * d; }
        vs += __shfl_xor(vs, 16, 64); vs += __shfl_xor(vs, 32, 64);
        const float rs = rsqrtf(vs * 0.0078125f + 1e-5f);
        float y[32];
        #pragma unroll
        for (int k = 0; k < 32; ++k) y[k] = (x[k] - mu) * rs * sc[k] + bi[k];
        #pragma unroll
        for (int u = 0; u < 4; ++u) {
            uint4 o;
            o.x = pk2(y[u*8+0], y[u*8+1]); o.y = pk2(y[u*8+2], y[u*8+3]);
            o.z = pk2(y[u*8+4], y[u*8+5]); o.w = pk2(y[u*8+6], y[u*8+7]);
            *(uint4*)(lntile + l15 * LDZ + quad * 32 + u * 8) = o;
        }
        #pragma unroll
        for (int ks = 0; ks < 4; ++ks)
            zfh[ks] = *(const bf16x8*)(lntile + l15 * LDZ + ks * 32 + quad * 8);
        #pragma unroll
        for (int k = 0; k < 32; ++k) y[k] -= b2f(f2b(y[k]));
        #pragma unroll
        for (int u = 0; u < 4; ++u) {
            uint4 o;
            o.x = pk2(y[u*8+0], y[u*8+1]); o.y = pk2(y[u*8+2], y[u*8+3]);
            o.z = pk2(y[u*8+4], y[u*8+5]); o.w = pk2(y[u*8+6], y[u*8+7]);
            *(uint4*)(lntile + l15 * LDZ + quad * 32 + u * 8) = o;
        }
        #pragma unroll
        for (int ks = 0; ks < 4; ++ks)
            zfl[ks] = *(const bf16x8*)(lntile + l15 * LDZ + ks * 32 + quad * 8);
    }
    __syncthreads();

    const float* Ws[4] = {Wq, Wk, Wv, Wg};
    u16* Os[4] = {Qo, Ko, Vo, Go};

    #pragma unroll 1
    for (int g = 0; g < 4; ++g) {
        const float* __restrict__ W = Ws[g];
        const bool three = (g < 2);
        // stage W [e][o] f32 -> bufH/bufL [o][e] bf16
        for (int c = t * 4; c < 16384; c += 2048) {
            const int e = c >> 7, o = c & 127;
            float4 w4 = *(const float4*)(W + c);
            const float w[4] = {w4.x, w4.y, w4.z, w4.w};
            #pragma unroll
            for (int j = 0; j < 4; ++j) {
                const u16 hi = f2b(w[j]);
                bufH[(o + j) * LDB + e] = hi;
                if (three) bufL[(o + j) * LDB + e] = f2b(w[j] - b2f(hi));
            }
        }
        __syncthreads();
        u16* __restrict__ O = Os[g];
        #pragma unroll
        for (int nt = 0; nt < 8; ++nt) {
            f32x4 ac = {0.f, 0.f, 0.f, 0.f};
            #pragma unroll
            for (int ks = 0; ks < 4; ++ks) {
                bf16x8 bh = *(const bf16x8*)(bufH + (nt * 16 + l15) * LDB + ks * 32 + quad * 8);
                ac = MFMA16(zfh[ks], bh, ac);
                if (three) {
                    bf16x8 bl = *(const bf16x8*)(bufL + (nt * 16 + l15) * LDB + ks * 32 + quad * 8);
                    ac = MFMA16(zfl[ks], bh, ac);
                    ac = MFMA16(zfh[ks], bl, ac);
                }
            }
            const int col = nt * 16 + l15;
            #pragma unroll
            for (int r = 0; r < 4; ++r) {
                float v = ac[r];
                if (g == 3) v = 1.f / (1.f + __expf(-(v + bg[col])));
                O[((size_t)(rowbase + quad * 4 + r) << 7) + col] = f2b(v);
            }
        }
        __syncthreads();
    }
}

// ===========================================================================
// K2: row-wise attention per (i,h). Grid 1024 x 512thr; wave = 32 q-rows.
// Q A-frags + gate direct from global; K/V staged in LDS; gw overwrites Q.
// LDS: kh(20480) + vt(16896) + myT(10240) = 47616 B.
// ===========================================================================
__global__ __launch_bounds__(512, 2) void k2_attn(
    u16* QG, const u16* __restrict__ K, const u16* __restrict__ V,
    const u16* __restrict__ G)
{
    __shared__ __attribute__((aligned(16))) u16 kh[256 * LDK];
    __shared__ __attribute__((aligned(16))) u16 vt[32 * LDV];
    __shared__ __attribute__((aligned(16))) u16 ptt[8 * 16 * LDQ];

    const int bid = blockIdx.x;
    const int i = bid >> 2, h = bid & 3;
    const int t = threadIdx.x;
    const int lane = t & 63;
    const int l15  = lane & 15;
    const int quad = lane >> 4;
    const int wave = t >> 6;
    u16* __restrict__ myT = ptt + wave * 16 * LDQ;
    const size_t rb = ((size_t)i) << 8;   // first token of row i

    // stage kh + vt: 2 threads per token
    {
        const int tok = t >> 1, half = t & 1;
        const u16* ksrc = K + ((rb + tok) << 7) + h * 32 + half * 16;
        #pragma unroll
        for (int u = 0; u < 2; ++u)
            *(uint4*)(kh + tok * LDK + half * 16 + u * 8) = *(const uint4*)(ksrc + u * 8);
        const u16* vsrc = V + ((rb + tok) << 7) + h * 32 + half * 16;
        #pragma unroll
        for (int u = 0; u < 2; ++u) {
            uint4 q = *(const uint4*)(vsrc + u * 8);
            u32 w4[4] = {q.x, q.y, q.z, q.w};
            #pragma unroll
            for (int k2 = 0; k2 < 4; ++k2) {
                vt[(half * 16 + u * 8 + k2 * 2    ) * LDV + tok] = (u16)(w4[k2] & 0xffffu);
                vt[(half * 16 + u * 8 + k2 * 2 + 1) * LDV + tok] = (u16)(w4[k2] >> 16);
            }
        }
    }
    // Q A-frags + gate from global (before any QG writes; per-wave-private rows)
    bf16x8 aq[2];
    f32x4  ga[2][2];
    #pragma unroll
    for (int it = 0; it < 2; ++it) {
        aq[it] = *(const bf16x8*)(QG + ((rb + wave * 32 + it * 16 + l15) << 7) + h * 32 + quad * 8);
        #pragma unroll
        for (int nt = 0; nt < 2; ++nt)
            #pragma unroll
            for (int r = 0; r < 4; ++r)
                ga[it][nt][r] = b2f(G[((rb + wave * 32 + it * 16 + quad * 4 + r) << 7) + h * 32 + nt * 16 + l15]);
    }
    __syncthreads();

    #pragma unroll 1
    for (int it = 0; it < 2; ++it) {
        f32x4 s[16];
        #pragma unroll
        for (int nt = 0; nt < 16; ++nt) {
            bf16x8 b = *(const bf16x8*)(kh + (nt * 16 + l15) * LDK + quad * 8);
            f32x4 zacc = {0.f, 0.f, 0.f, 0.f};
            s[nt] = MFMA16(aq[it], b, zacc);
        }
        float inv[4];
        #pragma unroll
        for (int r = 0; r < 4; ++r) {
            float mx = s[0][r];
            #pragma unroll
            for (int nt = 1; nt < 16; ++nt) mx = fmaxf(mx, s[nt][r]);
            #pragma unroll
            for (int m = 1; m < 16; m <<= 1) mx = fmaxf(mx, __shfl_xor(mx, m, 64));
            float sm = 0.f;
            #pragma unroll
            for (int nt = 0; nt < 16; ++nt) {
                float e = __expf(s[nt][r] - mx);
                s[nt][r] = e; sm += e;
            }
            #pragma unroll
            for (int m = 1; m < 16; m <<= 1) sm += __shfl_xor(sm, m, 64);
            inv[r] = 1.f / sm;
        }
        // PV in eight 32-col chunks through the per-wave 16x40 tile
        f32x4 o0 = {0.f,0.f,0.f,0.f}, o1 = {0.f,0.f,0.f,0.f};
        #pragma unroll
        for (int c8 = 0; c8 < 8; ++c8) {
            #pragma unroll
            for (int n2 = 0; n2 < 2; ++n2)
                #pragma unroll
                for (int r = 0; r < 4; ++r)
                    myT[(quad * 4 + r) * LDQ + n2 * 16 + l15] = f2b(s[c8 * 2 + n2][r]);
            bf16x8 a  = *(const bf16x8*)(myT + l15 * LDQ + quad * 8);
            bf16x8 b0 = *(const bf16x8*)(vt + (     l15) * LDV + c8 * 32 + quad * 8);
            bf16x8 b1 = *(const bf16x8*)(vt + (16 + l15) * LDV + c8 * 32 + quad * 8);
            o0 = MFMA16(a, b0, o0);
            o1 = MFMA16(a, b1, o1);
        }
        // normalize, gate, store gw over Q (own rows/cols only)
        #pragma unroll
        for (int r = 0; r < 4; ++r) {
            u16* dst = QG + ((rb + wave * 32 + it * 16 + quad * 4 + r) << 7) + h * 32;
            dst[l15]      = f2b(o0[r] * inv[r] * ga[it][0][r]);
            dst[16 + l15] = f2b(o1[r] * inv[r] * ga[it][1][r]);
        }
    }
}

// ===========================================================================
// K3: out = GW @ Wo + bo (f32). Grid 512 x 512thr; wave = 16 rows.
// A-frags direct from global; Wo^T staged bf16 in LDS (34816 B).
// ===========================================================================
__global__ __launch_bounds__(512, 2) void k3_out(
    const u16* __restrict__ GW, const float* __restrict__ Wo, const float* __restrict__ bo,
    float* __restrict__ out)
{
    __shared__ __attribute__((aligned(16))) u16 wt[128 * LDB];
    const int t = threadIdx.x;
    const int lane = t & 63;
    const int l15  = lane & 15;
    const int quad = lane >> 4;
    const int wave = t >> 6;
    const int rowbase = blockIdx.x * 128 + wave * 16;

    for (int c = t * 4; c < 16384; c += 2048) {
        const int k = c >> 7, n = c & 127;
        float4 w4 = *(const float4*)(Wo + c);
        wt[(n    ) * LDB + k] = f2b(w4.x);
        wt[(n + 1) * LDB + k] = f2b(w4.y);
        wt[(n + 2) * LDB + k] = f2b(w4.z);
        wt[(n + 3) * LDB + k] = f2b(w4.w);
    }
    __syncthreads();

    bf16x8 af[4];
    #pragma unroll
    for (int ks = 0; ks < 4; ++ks)
        af[ks] = *(const bf16x8*)(GW + ((size_t)(rowbase + l15) << 7) + ks * 32 + quad * 8);
    #pragma unroll
    for (int nt = 0; nt < 8; ++nt) {
        f32x4 ac = {0.f, 0.f, 0.f, 0.f};
        #pragma unroll
        for (int ks = 0; ks < 4; ++ks) {
            bf16x8 b = *(const bf16x8*)(wt + (nt * 16 + l15) * LDB + ks * 32 + quad * 8);
            ac = MFMA16(af[ks], b, ac);
        }
        const int col = nt * 16 + l15;
        const float bb = bo[col];
        #pragma unroll
        for (int r = 0; r < 4; ++r)
            out[((size_t)(rowbase + quad * 4 + r) << 7) + col] = ac[r] + bb;
    }
}

// ===========================================================================
// Fallback: R8 fused kernel (verbatim) for ws_size < 64 MiB.
// ===========================================================================
constexpr int FLDZ = 136;
constexpr int FLDW = 136;
constexpr int FLDO = 40;

__global__ __launch_bounds__(512, 2) void k_fused(
    const float* __restrict__ z, const float* __restrict__ lns, const float* __restrict__ lnb,
    const float* __restrict__ Wq, const float* __restrict__ Wk, const float* __restrict__ Wv,
    const float* __restrict__ Wg, const float* __restrict__ bg,
    const float* __restrict__ Wo, const float* __restrict__ bo,
    float* __restrict__ out)
{
    __shared__ __attribute__((aligned(16))) u16 smem[33280];
    const int i = blockIdx.x;
    const int t = threadIdx.x;
    const int lane = t & 63;
    const int l15  = lane & 15;
    const int quad = lane >> 4;
    const int wave = t >> 6;
    u16* __restrict__ kh   = smem;
    u16* __restrict__ vt   = smem + 10240;
    u16* __restrict__ bufA = smem + 18688;
    u16* __restrict__ myT  = smem + 23808 + wave * 16 * LDQ;
    u16* __restrict__ bufB = smem + 28928;
    u16* __restrict__ lntile = smem + wave * 16 * FLDZ;

    float4 wregA[2], wregB[2];
    auto prefW = [&](const float* __restrict__ W, int h, float4 (&r)[2]) {
        #pragma unroll
        for (int k2 = 0; k2 < 2; ++k2) {
            const int c = t * 4 + k2 * 2048;
            r[k2] = *(const float4*)(W + (c >> 5) * 128 + h * 32 + (c & 31));
        }
    };
    auto prefWoF = [&](int h, float4 (&r)[2]) {
        #pragma unroll
        for (int k2 = 0; k2 < 2; ++k2)
            r[k2] = *(const float4*)(Wo + h * 4096 + t * 4 + k2 * 2048);
    };
    auto stageHi = [&](u16* __restrict__ buf, const float4 (&r)[2]) {
        #pragma unroll
        for (int k2 = 0; k2 < 2; ++k2) {
            const int c = t * 4 + k2 * 2048;
            const int e = c >> 5, o = c & 31;
            buf[(o    ) * FLDW + e] = f2b(r[k2].x);
            buf[(o + 1) * FLDW + e] = f2b(r[k2].y);
            buf[(o + 2) * FLDW + e] = f2b(r[k2].z);
            buf[(o + 3) * FLDW + e] = f2b(r[k2].w);
        }
    };
    auto stageLo = [&](u16* __restrict__ buf, const float4 (&r)[2]) {
        #pragma unroll
        for (int k2 = 0; k2 < 2; ++k2) {
            const int c = t * 4 + k2 * 2048;
            const int e = c >> 5, o = c & 31;
            const float v0 = r[k2].x, v1 = r[k2].y, v2 = r[k2].z, v3 = r[k2].w;
            buf[(o    ) * FLDW + e] = f2b(v0 - b2f(f2b(v0)));
            buf[(o + 1) * FLDW + e] = f2b(v1 - b2f(f2b(v1)));
            buf[(o + 2) * FLDW + e] = f2b(v2 - b2f(f2b(v2)));
            buf[(o + 3) * FLDW + e] = f2b(v3 - b2f(f2b(v3)));
        }
    };
    auto stageWoL = [&](const float4 (&r)[2]) {
        #pragma unroll
        for (int k2 = 0; k2 < 2; ++k2) {
            const int c = t * 4 + k2 * 2048;
            const int kk = c >> 7, n = c & 127;
            bufA[(n    ) * FLDO + kk] = f2b(r[k2].x);
            bufA[(n + 1) * FLDO + kk] = f2b(r[k2].y);
            bufA[(n + 2) * FLDO + kk] = f2b(r[k2].z);
            bufA[(n + 3) * FLDO + kk] = f2b(r[k2].w);
        }
    };
    prefW(Wq, 0, wregA);
    bf16x8 zfh[2][4], zfl[2][4];
    {
        float sc[32], bi[32];
        #pragma unroll
        for (int u = 0; u < 8; ++u) {
            float4 s4 = *(const float4*)(lns + quad * 32 + u * 4);
            float4 b4 = *(const float4*)(lnb + quad * 32 + u * 4);
            sc[u*4+0]=s4.x; sc[u*4+1]=s4.y; sc[u*4+2]=s4.z; sc[u*4+3]=s4.w;
            bi[u*4+0]=b4.x; bi[u*4+1]=b4.y; bi[u*4+2]=b4.z; bi[u*4+3]=b4.w;
        }
        #pragma unroll 1
        for (int ms = 0; ms < 2; ++ms) {
            const size_t tok = (size_t)(i * 256 + wave * 32 + ms * 16 + l15);
            float x[32];
            #pragma unroll
            for (int u = 0; u < 8; ++u) {
                float4 v4 = *(const float4*)(z + (tok << 7) + quad * 32 + u * 4);
                x[u*4+0]=v4.x; x[u*4+1]=v4.y; x[u*4+2]=v4.z; x[u*4+3]=v4.w;
            }
            float s = 0.f;
            #pragma unroll
            for (int k = 0; k < 32; ++k) s += x[k];
            s += __shfl_xor(s, 16, 64); s += __shfl_xor(s, 32, 64);
            const float mu = s * 0.0078125f;
            float vs = 0.f;
            #pragma unroll
            for (int k = 0; k < 32; ++k) { float d = x[k] - mu; vs += d * d; }
            vs += __shfl_xor(vs, 16, 64); vs += __shfl_xor(vs, 32, 64);
            const float rs = rsqrtf(vs * 0.0078125f + 1e-5f);
            float y[32];
            #pragma unroll
            for (int k = 0; k < 32; ++k) y[k] = (x[k] - mu) * rs * sc[k] + bi[k];
            #pragma unroll
            for (int u = 0; u < 4; ++u) {
                uint4 o;
                o.x = pk2(y[u*8+0], y[u*8+1]); o.y = pk2(y[u*8+2], y[u*8+3]);
                o.z = pk2(y[u*8+4], y[u*8+5]); o.w = pk2(y[u*8+6], y[u*8+7]);
                *(uint4*)(lntile + l15 * FLDZ + quad * 32 + u * 8) = o;
            }
            #pragma unroll
            for (int ks = 0; ks < 4; ++ks)
                zfh[ms][ks] = *(const bf16x8*)(lntile + l15 * FLDZ + ks * 32 + quad * 8);
            #pragma unroll
            for (int k = 0; k < 32; ++k) y[k] -= b2f(f2b(y[k]));
            #pragma unroll
            for (int u = 0; u < 4; ++u) {
                uint4 o;
                o.x = pk2(y[u*8+0], y[u*8+1]); o.y = pk2(y[u*8+2], y[u*8+3]);
                o.z = pk2(y[u*8+4], y[u*8+5]); o.w = pk2(y[u*8+6], y[u*8+7]);
                *(uint4*)(lntile + l15 * FLDZ + quad * 32 + u * 8) = o;
            }
            #pragma unroll
            for (int ks = 0; ks < 4; ++ks)
                zfl[ms][ks] = *(const bf16x8*)(lntile + l15 * FLDZ + ks * 32 + quad * 8);
        }
    }
    __syncthreads();
    auto gemmAcc = [&](f32x4 (&acc)[2][2], bf16x8 (&af)[2][4], const u16* __restrict__ buf) {
        #pragma unroll
        for (int ms = 0; ms < 2; ++ms)
            #pragma unroll
            for (int nt = 0; nt < 2; ++nt) {
                f32x4 ac = acc[ms][nt];
                #pragma unroll
                for (int ks = 0; ks < 4; ++ks) {
                    bf16x8 b = *(const bf16x8*)(buf + (nt * 16 + l15) * FLDW + ks * 32 + quad * 8);
                    ac = MFMA16(af[ms][ks], b, ac);
                }
                acc[ms][nt] = ac;
            }
    };
    auto zero22 = [](f32x4 (&a)[2][2]) {
        #pragma unroll
        for (int ms = 0; ms < 2; ++ms)
            #pragma unroll
            for (int nt = 0; nt < 2; ++nt) a[ms][nt] = f32x4{0.f,0.f,0.f,0.f};
    };
    bf16x8 aq[2];
    f32x4  ga[2][2];
    f32x4  oacc[2][8];
    #pragma unroll
    for (int ms = 0; ms < 2; ++ms)
        #pragma unroll
        for (int nt = 0; nt < 8; ++nt)
            oacc[ms][nt] = f32x4{0.f, 0.f, 0.f, 0.f};
    #pragma unroll 1
    for (int h = 0; h < 4; ++h) {
        stageHi(bufA, wregA); stageLo(bufB, wregA);
        __syncthreads();
        prefW(Wk, h, wregA);
        {
            f32x4 qa[2][2]; zero22(qa);
            gemmAcc(qa, zfh, bufA); gemmAcc(qa, zfl, bufA); gemmAcc(qa, zfh, bufB);
            #pragma unroll
            for (int ms = 0; ms < 2; ++ms) {
                #pragma unroll
                for (int nt = 0; nt < 2; ++nt)
                    #pragma unroll
                    for (int r = 0; r < 4; ++r)
                        myT[(quad * 4 + r) * LDQ + nt * 16 + l15] = f2b(qa[ms][nt][r]);
                aq[ms] = *(const bf16x8*)(myT + l15 * LDQ + quad * 8);
            }
        }
        __syncthreads();
        stageHi(bufA, wregA); stageLo(bufB, wregA);
        __syncthreads();
        prefW(Wv, h, wregA); prefW(Wg, h, wregB);
        {
            f32x4 ka[2][2]; zero22(ka);
            gemmAcc(ka, zfh, bufA); gemmAcc(ka, zfl, bufA); gemmAcc(ka, zfh, bufB);
            #pragma unroll
            for (int ms = 0; ms < 2; ++ms)
                #pragma unroll
                for (int nt = 0; nt < 2; ++nt)
                    #pragma unroll
                    for (int r = 0; r < 4; ++r)
                        kh[(wave * 32 + ms * 16 + quad * 4 + r) * LDK + nt * 16 + l15] = f2b(ka[ms][nt][r]);
        }
        __syncthreads();
        stageHi(bufA, wregA); stageHi(bufB, wregB);
        __syncthreads();
        prefWoF(h, wregA);
        {
            f32x4 va[2][2]; zero22(va); gemmAcc(va, zfh, bufA);
            #pragma unroll
            for (int ms = 0; ms < 2; ++ms)
                #pragma unroll
                for (int nt = 0; nt < 2; ++nt)
                    #pragma unroll
                    for (int r = 0; r < 4; ++r)
                        vt[(nt * 16 + l15) * LDV + wave * 32 + ms * 16 + quad * 4 + r] = f2b(va[ms][nt][r]);
            zero22(ga); gemmAcc(ga, zfh, bufB);
            #pragma unroll
            for (int nt = 0; nt < 2; ++nt) {
                const float bb = bg[h * 32 + nt * 16 + l15];
                #pragma unroll
                for (int ms = 0; ms < 2; ++ms)
                    #pragma unroll
                    for (int r = 0; r < 4; ++r)
                        ga[ms][nt][r] = 1.f / (1.f + __expf(-(ga[ms][nt][r] + bb)));
            }
        }
        __syncthreads();
        stageWoL(wregA);
        __syncthreads();
        if (h < 3) prefW(Wq, h + 1, wregA);
        #pragma unroll 1
        for (int it = 0; it < 2; ++it) {
            f32x4 s[16];
            #pragma unroll
            for (int nt = 0; nt < 16; ++nt) {
                bf16x8 b = *(const bf16x8*)(kh + (nt * 16 + l15) * LDK + quad * 8);
                f32x4 zacc = {0.f, 0.f, 0.f, 0.f};
                s[nt] = MFMA16(aq[it], b, zacc);
            }
            float inv[4];
            #pragma unroll
            for (int r = 0; r < 4; ++r) {
                float mx = s[0][r];
                #pragma unroll
                for (int nt = 1; nt < 16; ++nt) mx = fmaxf(mx, s[nt][r]);
                #pragma unroll
                for (int m = 1; m < 16; m <<= 1) mx = fmaxf(mx, __shfl_xor(mx, m, 64));
                float sm = 0.f;
                #pragma unroll
                for (int nt = 0; nt < 16; ++nt) {
                    float e = __expf(s[nt][r] - mx);
                    s[nt][r] = e; sm += e;
                }
                #pragma unroll
                for (int m = 1; m < 16; m <<= 1) sm += __shfl_xor(sm, m, 64);
                inv[r] = 1.f / sm;
            }
            f32x4 o0 = {0.f,0.f,0.f,0.f}, o1 = {0.f,0.f,0.f,0.f};
            #pragma unroll
            for (int c8 = 0; c8 < 8; ++c8) {
                #pragma unroll
                for (int n2 = 0; n2 < 2; ++n2)
                    #pragma unroll
                    for (int r = 0; r < 4; ++r)
                        myT[(quad * 4 + r) * LDQ + n2 * 16 + l15] = f2b(s[c8 * 2 + n2][r]);
                bf16x8 a  = *(const bf16x8*)(myT + l15 * LDQ + quad * 8);
                bf16x8 b0 = *(const bf16x8*)(vt + (     l15) * LDV + c8 * 32 + quad * 8);
                bf16x8 b1 = *(const bf16x8*)(vt + (16 + l15) * LDV + c8 * 32 + quad * 8);
                o0 = MFMA16(a, b0, o0);
                o1 = MFMA16(a, b1, o1);
            }
            #pragma unroll
            for (int r = 0; r < 4; ++r) {
                myT[(quad * 4 + r) * LDQ + l15]      = f2b(o0[r] * inv[r] * ga[it][0][r]);
                myT[(quad * 4 + r) * LDQ + 16 + l15] = f2b(o1[r] * inv[r] * ga[it][1][r]);
            }
            bf16x8 agw = *(const bf16x8*)(myT + l15 * LDQ + quad * 8);
            #pragma unroll
            for (int nt = 0; nt < 8; ++nt) {
                bf16x8 bwo = *(const bf16x8*)(bufA + (nt * 16 + l15) * FLDO + quad * 8);
                oacc[it][nt] = MFMA16(agw, bwo, oacc[it][nt]);
            }
        }
        __syncthreads();
    }
    #pragma unroll
    for (int ms = 0; ms < 2; ++ms) {
        #pragma unroll
        for (int nt = 0; nt < 8; ++nt) {
            const int col = nt * 16 + l15;
            const float bb = bo[col];
            #pragma unroll
            for (int r = 0; r < 4; ++r) {
                const size_t row = (size_t)(i * 256 + wave * 32 + ms * 16 + quad * 4 + r);
                out[(row << 7) + col] = oacc[ms][nt][r] + bb;
            }
        }
    }
}

// ---------------------------------------------------------------------------
extern "C" void kernel_launch(void* const* d_in, const int* in_sizes, int n_in,
                              void* d_out, int out_size, void* d_ws, size_t ws_size,
                              hipStream_t stream)
{
    const float* z   = (const float*)d_in[0];
    const float* lns = (const float*)d_in[1];
    const float* lnb = (const float*)d_in[2];
    const float* Wq  = (const float*)d_in[3];
    const float* Wk  = (const float*)d_in[4];
    const float* Wv  = (const float*)d_in[5];
    const float* Wg  = (const float*)d_in[6];
    const float* bg  = (const float*)d_in[7];
    const float* Wo  = (const float*)d_in[8];
    const float* bo  = (const float*)d_in[9];
    float* out = (float*)d_out;

    const size_t NEED = 4ull * 65536 * 128 * 2;   // 64 MiB: Q,K,V,G bf16
    if (ws_size >= NEED) {
        u16* Qb = (u16*)d_ws;
        u16* Kb = Qb + 65536ull * 128;
        u16* Vb = Kb + 65536ull * 128;
        u16* Gb = Vb + 65536ull * 128;
        k1_proj<<<512, 512, 0, stream>>>(z, lns, lnb, Wq, Wk, Wv, Wg, bg, Qb, Kb, Vb, Gb);
        k2_attn<<<1024, 512, 0, stream>>>(Qb, Kb, Vb, Gb);
        k3_out<<<512, 512, 0, stream>>>(Qb, Wo, bo, out);
    } else {
        k_fused<<<256, 512, 0, stream>>>(z, lns, lnb, Wq, Wk, Wv, Wg, bg, Wo, bo, out);
    }
}